// Round 1
// baseline (545.827 us; speedup 1.0000x reference)
//
#include <hip/hip_runtime.h>
#include <math.h>

#define NB 2
#define NS 2048
#define NHID 768
#define NH 12
#define NDH 64
#define NWIN 128

// ---------------- RoPE cos/sin table (double precision for accuracy) ----------------
__global__ void k_rope_table(float* __restrict__ ct, float* __restrict__ st) {
    int idx = blockIdx.x * 256 + threadIdx.x;
    if (idx >= NS * 32) return;
    int s = idx >> 5, f = idx & 31;
    double inv = pow(10000.0, -((double)(2 * f)) / 64.0);
    double ang = (double)s * inv;
    ct[idx] = (float)cos(ang);
    st[idx] = (float)sin(ang);
}

// ---------------- RoPE apply: r = rope(x), per head (rotate-half over DH=64) --------
__global__ void k_rope(const float* __restrict__ x, const float* __restrict__ ct,
                       const float* __restrict__ st, float* __restrict__ r) {
    int idx = blockIdx.x * 256 + threadIdx.x;  // over B*S*H*32 pairs
    if (idx >= NB * NS * NH * 32) return;
    int f = idx & 31;
    int h = (idx >> 5) % NH;
    int bs = idx / (32 * NH);       // b*NS + s
    int s = bs & (NS - 1);
    int base = bs * NHID + h * NDH;
    float x1 = x[base + f], x2 = x[base + 32 + f];
    float c = ct[(s << 5) + f], sn = st[(s << 5) + f];
    r[base + f]      = x1 * c - x2 * sn;
    r[base + 32 + f] = x2 * c + x1 * sn;
}

// ---------------- fp32 GEMM: C[M=4096][768] = (A[4096][768]*W[768][768] + bias)*scale
// 128x128 tile, BK=16, 256 threads, 8x8 micro-tile.
__global__ __launch_bounds__(256) void k_gemm(const float* __restrict__ A,
                                              const float* __restrict__ W,
                                              const float* __restrict__ bias,
                                              float* __restrict__ C, float scale) {
    __shared__ __attribute__((aligned(16))) float As[16][132]; // As[k][m], stride 528B (16B-aligned rows)
    __shared__ __attribute__((aligned(16))) float Bs[16][132]; // Bs[k][n]
    int t = threadIdx.x;
    int m0 = blockIdx.y * 128, n0 = blockIdx.x * 128;
    int ty = t >> 4, tx = t & 15;
    int arow = t >> 1, ahalf = t & 1;    // A tile: 2 threads/row, 8 floats each
    int brow = t >> 4, bpart = t & 15;   // W tile: 16 threads/row, 8 floats each
    float acc[8][8] = {};
    for (int k0 = 0; k0 < NHID; k0 += 16) {
        const float4* ap = (const float4*)(A + (size_t)(m0 + arow) * NHID + k0 + ahalf * 8);
        float4 a0 = ap[0], a1 = ap[1];
        const float4* wp = (const float4*)(W + (size_t)(k0 + brow) * NHID + n0 + bpart * 8);
        float4 b0 = wp[0], b1 = wp[1];
        __syncthreads();   // previous iteration's compute reads done
        int kc = ahalf * 8;
        As[kc + 0][arow] = a0.x; As[kc + 1][arow] = a0.y;
        As[kc + 2][arow] = a0.z; As[kc + 3][arow] = a0.w;
        As[kc + 4][arow] = a1.x; As[kc + 5][arow] = a1.y;
        As[kc + 6][arow] = a1.z; As[kc + 7][arow] = a1.w;
        *(float4*)&Bs[brow][bpart * 8]     = b0;
        *(float4*)&Bs[brow][bpart * 8 + 4] = b1;
        __syncthreads();
#pragma unroll
        for (int kk = 0; kk < 16; ++kk) {
            float4 av0 = *(const float4*)&As[kk][ty * 8];
            float4 av1 = *(const float4*)&As[kk][ty * 8 + 4];
            float4 bv0 = *(const float4*)&Bs[kk][tx * 8];
            float4 bv1 = *(const float4*)&Bs[kk][tx * 8 + 4];
            float av[8] = {av0.x, av0.y, av0.z, av0.w, av1.x, av1.y, av1.z, av1.w};
            float bv[8] = {bv0.x, bv0.y, bv0.z, bv0.w, bv1.x, bv1.y, bv1.z, bv1.w};
#pragma unroll
            for (int i = 0; i < 8; ++i)
#pragma unroll
                for (int j = 0; j < 8; ++j)
                    acc[i][j] = fmaf(av[i], bv[j], acc[i][j]);
        }
    }
#pragma unroll
    for (int i = 0; i < 8; ++i) {
        int m = m0 + ty * 8 + i;
#pragma unroll
        for (int j = 0; j < 8; ++j) {
            int n = n0 + tx * 8 + j;
            C[(size_t)m * NHID + n] = (acc[i][j] + bias[n]) * scale;
        }
    }
}

// ---------------- sliding-window flash attention --------------------------------
// One block per (b, h, 64-query tile). 5 key tiles of 64 cover |i-j|<128.
// 256 threads as 16x16 grid, each computing a 4x4 sub-tile.
__global__ __launch_bounds__(256) void k_attn(const float* __restrict__ q,
                                              const float* __restrict__ kmat,
                                              const float* __restrict__ vmat,
                                              const int* __restrict__ am,
                                              float* __restrict__ o) {
    __shared__ float qs[64][65];
    __shared__ float ks[64][65];   // reused as P (probabilities) after score phase
    __shared__ float vs[64][65];
    __shared__ float mrow[64], lrow[64], arw[64];
    int t = threadIdx.x;
    int qb = blockIdx.x, h = blockIdx.y, b = blockIdx.z;
    int i0 = qb * 64;
    int lr = t >> 2, lp = t & 3;   // loads: 4 threads per row, 16 floats each
    {
        const float* qp = q + ((size_t)(b * NS + i0 + lr)) * NHID + h * NDH + lp * 16;
#pragma unroll
        for (int u = 0; u < 4; ++u) {
            float4 vv = ((const float4*)qp)[u];
            int c = lp * 16 + u * 4;
            qs[lr][c + 0] = vv.x; qs[lr][c + 1] = vv.y;
            qs[lr][c + 2] = vv.z; qs[lr][c + 3] = vv.w;
        }
    }
    if (t < 64) { mrow[t] = -1e30f; lrow[t] = 0.0f; arw[t] = 1.0f; }
    int ty = t >> 4, tx = t & 15;
    float acc[4][4] = {};
    __syncthreads();

    for (int kt = 0; kt < 5; ++kt) {
        int j0 = i0 - 128 + kt * 64;
        if (j0 + 64 <= 0 || j0 >= NS) continue;   // uniform per block
        {   // load K,V tile (zero-fill out-of-range rows)
            int j = j0 + lr;
            bool okr = (j >= 0 && j < NS);
            const float* kp = kmat + ((size_t)(b * NS + j)) * NHID + h * NDH + lp * 16;
            const float* vp = vmat + ((size_t)(b * NS + j)) * NHID + h * NDH + lp * 16;
#pragma unroll
            for (int u = 0; u < 4; ++u) {
                float4 kv = okr ? ((const float4*)kp)[u] : float4{0, 0, 0, 0};
                float4 vv = okr ? ((const float4*)vp)[u] : float4{0, 0, 0, 0};
                int c = lp * 16 + u * 4;
                ks[lr][c + 0] = kv.x; ks[lr][c + 1] = kv.y;
                ks[lr][c + 2] = kv.z; ks[lr][c + 3] = kv.w;
                vs[lr][c + 0] = vv.x; vs[lr][c + 1] = vv.y;
                vs[lr][c + 2] = vv.z; vs[lr][c + 3] = vv.w;
            }
        }
        __syncthreads();
        // scores: sv[i][j] = q_row . k_col  (q pre-scaled by 1/sqrt(64))
        float sv[4][4] = {};
#pragma unroll 8
        for (int kk = 0; kk < 64; ++kk) {
            float qv[4], kv[4];
#pragma unroll
            for (int i = 0; i < 4; ++i) qv[i] = qs[ty * 4 + i][kk];
#pragma unroll
            for (int j = 0; j < 4; ++j) kv[j] = ks[tx * 4 + j][kk];
#pragma unroll
            for (int i = 0; i < 4; ++i)
#pragma unroll
                for (int j = 0; j < 4; ++j)
                    sv[i][j] = fmaf(qv[i], kv[j], sv[i][j]);
        }
        // mask: pad AND window; -inf so masked entries contribute exactly 0
#pragma unroll
        for (int j = 0; j < 4; ++j) {
            int kj = j0 + tx * 4 + j;
            bool okj = (kj >= 0 && kj < NS) && (am[b * NS + kj] != 0);
#pragma unroll
            for (int i = 0; i < 4; ++i) {
                int qi = i0 + ty * 4 + i;
                int d = qi - kj; if (d < 0) d = -d;
                if (!okj || d >= NWIN) sv[i][j] = -INFINITY;
            }
        }
        // online softmax: each row owned by 16 consecutive lanes (same wave)
        float pl[4][4], alpha_l[4], mnew_l[4], psum_l[4];
#pragma unroll
        for (int i = 0; i < 4; ++i) {
            float tmax = fmaxf(fmaxf(sv[i][0], sv[i][1]), fmaxf(sv[i][2], sv[i][3]));
#pragma unroll
            for (int w = 1; w < 16; w <<= 1) tmax = fmaxf(tmax, __shfl_xor(tmax, w, 64));
            int row = ty * 4 + i;
            float mold = mrow[row];
            float mnew = fmaxf(mold, tmax);
            float s = 0.f;
#pragma unroll
            for (int j = 0; j < 4; ++j) { float p = expf(sv[i][j] - mnew); pl[i][j] = p; s += p; }
#pragma unroll
            for (int w = 1; w < 16; w <<= 1) s += __shfl_xor(s, w, 64);
            alpha_l[i] = expf(mold - mnew);
            mnew_l[i] = mnew; psum_l[i] = s;
        }
        __syncthreads();   // all ks/mrow reads done; safe to overwrite
        if (tx == 0) {
#pragma unroll
            for (int i = 0; i < 4; ++i) {
                int row = ty * 4 + i;
                mrow[row] = mnew_l[i];
                lrow[row] = lrow[row] * alpha_l[i] + psum_l[i];
                arw[row] = alpha_l[i];
            }
        }
#pragma unroll
        for (int i = 0; i < 4; ++i)
#pragma unroll
            for (int j = 0; j < 4; ++j)
                ks[ty * 4 + i][tx * 4 + j] = pl[i][j];   // P into ks buffer
        __syncthreads();
        // rescale accumulator + PV
#pragma unroll
        for (int i = 0; i < 4; ++i) {
            float al = arw[ty * 4 + i];
#pragma unroll
            for (int j = 0; j < 4; ++j) acc[i][j] *= al;
        }
#pragma unroll 8
        for (int c = 0; c < 64; ++c) {
            float pv[4], vv[4];
#pragma unroll
            for (int i = 0; i < 4; ++i) pv[i] = ks[ty * 4 + i][c];
#pragma unroll
            for (int j = 0; j < 4; ++j) vv[j] = vs[c][tx * 4 + j];
#pragma unroll
            for (int i = 0; i < 4; ++i)
#pragma unroll
                for (int j = 0; j < 4; ++j)
                    acc[i][j] = fmaf(pv[i], vv[j], acc[i][j]);
        }
        __syncthreads();   // before next tile's loads overwrite ks/vs
    }
#pragma unroll
    for (int i = 0; i < 4; ++i) {
        int row = ty * 4 + i;
        float inv_l = 1.0f / lrow[row];
#pragma unroll
        for (int j = 0; j < 4; ++j)
            o[((size_t)(b * NS + i0 + row)) * NHID + h * NDH + tx * 4 + j] = acc[i][j] * inv_l;
    }
}

extern "C" void kernel_launch(void* const* d_in, const int* in_sizes, int n_in,
                              void* d_out, int out_size, void* d_ws, size_t ws_size,
                              hipStream_t stream) {
    (void)in_sizes; (void)n_in; (void)out_size; (void)ws_size;
    const float* x  = (const float*)d_in[0];
    const int*   am = (const int*)d_in[1];
    const float* Wq = (const float*)d_in[2];
    const float* bq = (const float*)d_in[3];
    const float* Wk = (const float*)d_in[4];
    const float* bk = (const float*)d_in[5];
    const float* Wv = (const float*)d_in[6];
    const float* bv = (const float*)d_in[7];
    const float* Wo = (const float*)d_in[8];
    const float* bo = (const float*)d_in[9];
    float* out = (float*)d_out;
    float* ws  = (float*)d_ws;

    // workspace layout (floats)
    float* ct = ws;                    // 2048*32
    float* st = ws + 65536;            // 2048*32
    float* r  = ws + 131072;           // 4096*768 roped input
    float* qb = ws + 3276800;          // 4096*768
    float* kb = ws + 6422528;          // 4096*768
    float* vb = ws + 9568256;          // 4096*768
    float* ao = ws + 12713984;         // 4096*768 attention output

    k_rope_table<<<256, 256, 0, stream>>>(ct, st);
    k_rope<<<(NB * NS * NH * 32 + 255) / 256, 256, 0, stream>>>(x, ct, st, r);
    dim3 gg(6, 32);
    k_gemm<<<gg, 256, 0, stream>>>(r,  Wq, bq, qb, 0.125f);   // scale = 1/sqrt(64)
    k_gemm<<<gg, 256, 0, stream>>>(r,  Wk, bk, kb, 1.0f);
    k_gemm<<<gg, 256, 0, stream>>>(x,  Wv, bv, vb, 1.0f);
    dim3 ga(NS / 64, NH, NB);
    k_attn<<<ga, 256, 0, stream>>>(qb, kb, vb, am, ao);
    k_gemm<<<gg, 256, 0, stream>>>(ao, Wo, bo, out, 1.0f);
}

// Round 2
// 205.903 us; speedup vs baseline: 2.6509x; 2.6509x over previous
//
#include <hip/hip_runtime.h>
#include <hip/hip_bf16.h>
#include <math.h>

#define NB 2
#define NS 2048
#define NHID 768
#define NH 12
#define NDH 64
#define NWIN 128

typedef __attribute__((ext_vector_type(8))) short bf16x8;
typedef __attribute__((ext_vector_type(4))) float f32x4;

__device__ inline unsigned short f2b(float f) {
    union { float f; unsigned int i; } x; x.f = f;
    unsigned int r = x.i + 0x7FFFu + ((x.i >> 16) & 1u);   // RNE
    return (unsigned short)(r >> 16);
}
__device__ inline void unpack2(unsigned int w, float& lo, float& hi) {
    union { unsigned int i; float f; } a, b;
    a.i = w << 16; b.i = w & 0xFFFF0000u;
    lo = a.f; hi = b.f;
}

// ---------------- RoPE cos/sin table (double precision) ----------------
__global__ void k_rope_table(float* __restrict__ ct, float* __restrict__ st) {
    int idx = blockIdx.x * 256 + threadIdx.x;
    if (idx >= NS * 32) return;
    int s = idx >> 5, f = idx & 31;
    double inv = pow(10000.0, -((double)(2 * f)) / 64.0);
    double ang = (double)s * inv;
    ct[idx] = (float)cos(ang);
    st[idx] = (float)sin(ang);
}

// ---------------- RoPE apply, output bf16 ----------------
__global__ void k_rope(const float* __restrict__ x, const float* __restrict__ ct,
                       const float* __restrict__ st, __hip_bfloat16* __restrict__ r) {
    int idx = blockIdx.x * 256 + threadIdx.x;  // B*S*H*32 pairs
    if (idx >= NB * NS * NH * 32) return;
    int f = idx & 31;
    int h = (idx >> 5) % NH;
    int bs = idx / (32 * NH);
    int s = bs & (NS - 1);
    int base = bs * NHID + h * NDH;
    float x1 = x[base + f], x2 = x[base + 32 + f];
    float c = ct[(s << 5) + f], sn = st[(s << 5) + f];
    ((unsigned short*)r)[base + f]      = f2b(x1 * c - x2 * sn);
    ((unsigned short*)r)[base + 32 + f] = f2b(x2 * c + x1 * sn);
}

// ---------------- fp32 -> bf16 convert (vectorized) ----------------
__global__ void k_conv(const float* __restrict__ x, __hip_bfloat16* __restrict__ y, int n4) {
    int i = blockIdx.x * 256 + threadIdx.x;
    if (i >= n4) return;
    float4 f = ((const float4*)x)[i];
    ushort4 u = { f2b(f.x), f2b(f.y), f2b(f.z), f2b(f.w) };
    *(ushort4*)((unsigned short*)y + 4 * (size_t)i) = u;
}

// ---------------- weight transpose + convert: Wt[n][k] = bf16(W[k][n]) ----------------
__global__ __launch_bounds__(256) void k_convT(const float* __restrict__ w0, const float* __restrict__ w1,
                                               const float* __restrict__ w2, const float* __restrict__ w3,
                                               __hip_bfloat16* o0, __hip_bfloat16* o1,
                                               __hip_bfloat16* o2, __hip_bfloat16* o3) {
    const float* W; __hip_bfloat16* O;
    switch (blockIdx.z) {
        case 0: W = w0; O = o0; break;
        case 1: W = w1; O = o1; break;
        case 2: W = w2; O = o2; break;
        default: W = w3; O = o3; break;
    }
    __shared__ float tile[64][65];
    int k0 = blockIdx.x * 64, n0 = blockIdx.y * 64;
    int t = threadIdx.x;
    int rr = t >> 4, cc = (t & 15) * 4;
#pragma unroll
    for (int u = 0; u < 4; ++u) {
        int row = rr + u * 16;
        float4 f = *(const float4*)(W + (size_t)(k0 + row) * NHID + n0 + cc);
        tile[row][cc] = f.x; tile[row][cc + 1] = f.y;
        tile[row][cc + 2] = f.z; tile[row][cc + 3] = f.w;
    }
    __syncthreads();
#pragma unroll
    for (int u = 0; u < 4; ++u) {
        int n = rr + u * 16;
        ushort4 s = { f2b(tile[cc + 0][n]), f2b(tile[cc + 1][n]),
                      f2b(tile[cc + 2][n]), f2b(tile[cc + 3][n]) };
        *(ushort4*)((unsigned short*)O + (size_t)(n0 + n) * NHID + k0 + cc) = s;
    }
}

// ---------------- bf16 MFMA GEMM: C[4096][768] = (A[4096][768] x Wt^T + bias)*scale
// A row-major [M][K] bf16; Wt row-major [N][K] bf16. 128x128 tile, BK=32,
// 4 waves (2x2), 64x64 per wave, 16x16x32 MFMA.
__global__ __launch_bounds__(256) void k_gemm_mfma(const __hip_bfloat16* __restrict__ A,
                                                   const __hip_bfloat16* __restrict__ Wt,
                                                   const float* __restrict__ bias,
                                                   __hip_bfloat16* __restrict__ Cb,
                                                   float* __restrict__ Cf, float scale) {
    __shared__ unsigned short As[128][40];   // rows padded to 80B: conflict-free b64 frag reads
    __shared__ unsigned short Bs[128][40];
    const int t = threadIdx.x;
    const int m0 = blockIdx.y * 128, n0 = blockIdx.x * 128;
    const int wid = t >> 6, lane = t & 63;
    const int wm = (wid >> 1) * 64, wn = (wid & 1) * 64;
    const int g = lane >> 4, r16 = lane & 15;

    f32x4 acc[4][4];
#pragma unroll
    for (int i = 0; i < 4; ++i)
#pragma unroll
        for (int j = 0; j < 4; ++j) acc[i][j] = (f32x4){0.f, 0.f, 0.f, 0.f};

    const int srow = t >> 2, spart = t & 3;   // 64 rows x 4 parts per 256 threads
    const __hip_bfloat16* aP = A + (size_t)(m0 + srow) * NHID + spart * 8;
    const __hip_bfloat16* bP = Wt + (size_t)(n0 + srow) * NHID + spart * 8;

    uint4 ra0 = *(const uint4*)(aP);
    uint4 ra1 = *(const uint4*)(aP + 64 * NHID);
    uint4 rb0 = *(const uint4*)(bP);
    uint4 rb1 = *(const uint4*)(bP + 64 * NHID);

    union Frag { bf16x8 v; unsigned long long q[2]; };

    for (int ks = 0; ks < 24; ++ks) {
        __syncthreads();
        *(uint4*)&As[srow][spart * 8]      = ra0;
        *(uint4*)&As[srow + 64][spart * 8] = ra1;
        *(uint4*)&Bs[srow][spart * 8]      = rb0;
        *(uint4*)&Bs[srow + 64][spart * 8] = rb1;
        __syncthreads();
        if (ks < 23) {
            const __hip_bfloat16* a2 = aP + (ks + 1) * 32;
            const __hip_bfloat16* b2 = bP + (ks + 1) * 32;
            ra0 = *(const uint4*)(a2);
            ra1 = *(const uint4*)(a2 + 64 * NHID);
            rb0 = *(const uint4*)(b2);
            rb1 = *(const uint4*)(b2 + 64 * NHID);
        }
        Frag af[4], bf[4];
#pragma unroll
        for (int mi = 0; mi < 4; ++mi) {
            const unsigned short* p = &As[wm + mi * 16 + r16][0];
            af[mi].q[0] = *(const unsigned long long*)(p + 4 * g);
            af[mi].q[1] = *(const unsigned long long*)(p + 16 + 4 * g);
        }
#pragma unroll
        for (int ni = 0; ni < 4; ++ni) {
            const unsigned short* p = &Bs[wn + ni * 16 + r16][0];
            bf[ni].q[0] = *(const unsigned long long*)(p + 4 * g);
            bf[ni].q[1] = *(const unsigned long long*)(p + 16 + 4 * g);
        }
#pragma unroll
        for (int mi = 0; mi < 4; ++mi)
#pragma unroll
            for (int ni = 0; ni < 4; ++ni)
                acc[mi][ni] = __builtin_amdgcn_mfma_f32_16x16x32_bf16(af[mi].v, bf[ni].v, acc[mi][ni], 0, 0, 0);
    }

#pragma unroll
    for (int mi = 0; mi < 4; ++mi)
#pragma unroll
        for (int ni = 0; ni < 4; ++ni)
#pragma unroll
            for (int r = 0; r < 4; ++r) {
                int m = m0 + wm + mi * 16 + 4 * g + r;
                int n = n0 + wn + ni * 16 + r16;
                float v = (acc[mi][ni][r] + bias[n]) * scale;
                if (Cb) ((unsigned short*)Cb)[(size_t)m * NHID + n] = f2b(v);
                else    Cf[(size_t)m * NHID + n] = v;
            }
}

// ---------------- sliding-window flash attention (bf16 in/out, fp32 math) ------------
__global__ __launch_bounds__(256) void k_attn(const __hip_bfloat16* __restrict__ q,
                                              const __hip_bfloat16* __restrict__ kmat,
                                              const __hip_bfloat16* __restrict__ vmat,
                                              const int* __restrict__ am,
                                              __hip_bfloat16* __restrict__ o) {
    __shared__ float qs[64][65];
    __shared__ float ks[64][65];
    __shared__ float vs[64][65];
    __shared__ float mrow[64], lrow[64], arw[64];
    int t = threadIdx.x;
    int qb = blockIdx.x, h = blockIdx.y, b = blockIdx.z;
    int i0 = qb * 64;
    int lr = t >> 2, lp = t & 3;   // 4 threads/row, 16 bf16 each
    {
        const __hip_bfloat16* qp = q + ((size_t)(b * NS + i0 + lr)) * NHID + h * NDH + lp * 16;
        uint4 u0 = *(const uint4*)qp;
        uint4 u1 = *(const uint4*)(qp + 8);
        unsigned int ww[8] = {u0.x, u0.y, u0.z, u0.w, u1.x, u1.y, u1.z, u1.w};
#pragma unroll
        for (int j = 0; j < 8; ++j) {
            float lo, hi; unpack2(ww[j], lo, hi);
            qs[lr][lp * 16 + 2 * j] = lo; qs[lr][lp * 16 + 2 * j + 1] = hi;
        }
    }
    if (t < 64) { mrow[t] = -1e30f; lrow[t] = 0.0f; arw[t] = 1.0f; }
    int ty = t >> 4, tx = t & 15;
    float acc[4][4] = {};
    __syncthreads();

    for (int kt = 0; kt < 5; ++kt) {
        int j0 = i0 - 128 + kt * 64;
        if (j0 + 64 <= 0 || j0 >= NS) continue;
        {
            int j = j0 + lr;
            bool okr = (j >= 0 && j < NS);
            const __hip_bfloat16* kp = kmat + ((size_t)(b * NS + j)) * NHID + h * NDH + lp * 16;
            const __hip_bfloat16* vp = vmat + ((size_t)(b * NS + j)) * NHID + h * NDH + lp * 16;
            uint4 z = {0, 0, 0, 0};
            uint4 k0v = okr ? *(const uint4*)kp : z;
            uint4 k1v = okr ? *(const uint4*)(kp + 8) : z;
            uint4 v0v = okr ? *(const uint4*)vp : z;
            uint4 v1v = okr ? *(const uint4*)(vp + 8) : z;
            unsigned int wk[8] = {k0v.x, k0v.y, k0v.z, k0v.w, k1v.x, k1v.y, k1v.z, k1v.w};
            unsigned int wv[8] = {v0v.x, v0v.y, v0v.z, v0v.w, v1v.x, v1v.y, v1v.z, v1v.w};
#pragma unroll
            for (int j2 = 0; j2 < 8; ++j2) {
                float lo, hi;
                unpack2(wk[j2], lo, hi);
                ks[lr][lp * 16 + 2 * j2] = lo; ks[lr][lp * 16 + 2 * j2 + 1] = hi;
                unpack2(wv[j2], lo, hi);
                vs[lr][lp * 16 + 2 * j2] = lo; vs[lr][lp * 16 + 2 * j2 + 1] = hi;
            }
        }
        __syncthreads();
        float sv[4][4] = {};
#pragma unroll 8
        for (int kk = 0; kk < 64; ++kk) {
            float qv[4], kv[4];
#pragma unroll
            for (int i = 0; i < 4; ++i) qv[i] = qs[ty * 4 + i][kk];
#pragma unroll
            for (int j = 0; j < 4; ++j) kv[j] = ks[tx * 4 + j][kk];
#pragma unroll
            for (int i = 0; i < 4; ++i)
#pragma unroll
                for (int j = 0; j < 4; ++j)
                    sv[i][j] = fmaf(qv[i], kv[j], sv[i][j]);
        }
#pragma unroll
        for (int j = 0; j < 4; ++j) {
            int kj = j0 + tx * 4 + j;
            bool okj = (kj >= 0 && kj < NS) && (am[b * NS + kj] != 0);
#pragma unroll
            for (int i = 0; i < 4; ++i) {
                int qi = i0 + ty * 4 + i;
                int d = qi - kj; if (d < 0) d = -d;
                if (!okj || d >= NWIN) sv[i][j] = -INFINITY;
            }
        }
        float pl[4][4], alpha_l[4], mnew_l[4], psum_l[4];
#pragma unroll
        for (int i = 0; i < 4; ++i) {
            float tmax = fmaxf(fmaxf(sv[i][0], sv[i][1]), fmaxf(sv[i][2], sv[i][3]));
#pragma unroll
            for (int w = 1; w < 16; w <<= 1) tmax = fmaxf(tmax, __shfl_xor(tmax, w, 64));
            int row = ty * 4 + i;
            float mold = mrow[row];
            float mnew = fmaxf(mold, tmax);
            float s = 0.f;
#pragma unroll
            for (int j = 0; j < 4; ++j) { float p = expf(sv[i][j] - mnew); pl[i][j] = p; s += p; }
#pragma unroll
            for (int w = 1; w < 16; w <<= 1) s += __shfl_xor(s, w, 64);
            alpha_l[i] = expf(mold - mnew);
            mnew_l[i] = mnew; psum_l[i] = s;
        }
        __syncthreads();
        if (tx == 0) {
#pragma unroll
            for (int i = 0; i < 4; ++i) {
                int row = ty * 4 + i;
                mrow[row] = mnew_l[i];
                lrow[row] = lrow[row] * alpha_l[i] + psum_l[i];
                arw[row] = alpha_l[i];
            }
        }
#pragma unroll
        for (int i = 0; i < 4; ++i)
#pragma unroll
            for (int j = 0; j < 4; ++j)
                ks[ty * 4 + i][tx * 4 + j] = pl[i][j];
        __syncthreads();
#pragma unroll
        for (int i = 0; i < 4; ++i) {
            float al = arw[ty * 4 + i];
#pragma unroll
            for (int j = 0; j < 4; ++j) acc[i][j] *= al;
        }
#pragma unroll 8
        for (int c = 0; c < 64; ++c) {
            float pv[4], vv[4];
#pragma unroll
            for (int i = 0; i < 4; ++i) pv[i] = ks[ty * 4 + i][c];
#pragma unroll
            for (int j = 0; j < 4; ++j) vv[j] = vs[c][tx * 4 + j];
#pragma unroll
            for (int i = 0; i < 4; ++i)
#pragma unroll
                for (int j = 0; j < 4; ++j)
                    acc[i][j] = fmaf(pv[i], vv[j], acc[i][j]);
        }
        __syncthreads();
    }
#pragma unroll
    for (int i = 0; i < 4; ++i) {
        int row = ty * 4 + i;
        float inv_l = 1.0f / lrow[row];
#pragma unroll
        for (int j = 0; j < 4; ++j)
            ((unsigned short*)o)[((size_t)(b * NS + i0 + row)) * NHID + h * NDH + tx * 4 + j] =
                f2b(acc[i][j] * inv_l);
    }
}

extern "C" void kernel_launch(void* const* d_in, const int* in_sizes, int n_in,
                              void* d_out, int out_size, void* d_ws, size_t ws_size,
                              hipStream_t stream) {
    (void)in_sizes; (void)n_in; (void)out_size; (void)ws_size;
    const float* x  = (const float*)d_in[0];
    const int*   am = (const int*)d_in[1];
    const float* Wq = (const float*)d_in[2];
    const float* bq = (const float*)d_in[3];
    const float* Wk = (const float*)d_in[4];
    const float* bk = (const float*)d_in[5];
    const float* Wv = (const float*)d_in[6];
    const float* bv = (const float*)d_in[7];
    const float* Wo = (const float*)d_in[8];
    const float* bo = (const float*)d_in[9];
    float* out = (float*)d_out;
    float* ws  = (float*)d_ws;

    // workspace layout (float units)
    float* ct = ws;                                   // 65536
    float* st = ws + 65536;                           // 65536
    __hip_bfloat16* rb  = (__hip_bfloat16*)(ws + 131072);    // 4096x768 bf16
    __hip_bfloat16* xb  = (__hip_bfloat16*)(ws + 1703936);
    __hip_bfloat16* WtQ = (__hip_bfloat16*)(ws + 3276800);   // 768x768 bf16 each
    __hip_bfloat16* WtK = (__hip_bfloat16*)(ws + 3571712);
    __hip_bfloat16* WtV = (__hip_bfloat16*)(ws + 3866624);
    __hip_bfloat16* WtO = (__hip_bfloat16*)(ws + 4161536);
    __hip_bfloat16* qb  = (__hip_bfloat16*)(ws + 4456448);   // 4096x768 bf16
    __hip_bfloat16* kb  = (__hip_bfloat16*)(ws + 6029312);
    __hip_bfloat16* vb  = (__hip_bfloat16*)(ws + 7602176);
    __hip_bfloat16* aob = (__hip_bfloat16*)(ws + 9175040);

    k_rope_table<<<256, 256, 0, stream>>>(ct, st);
    k_rope<<<(NB * NS * NH * 32 + 255) / 256, 256, 0, stream>>>(x, ct, st, rb);
    k_conv<<<(NB * NS * NHID / 4 + 255) / 256, 256, 0, stream>>>(x, xb, NB * NS * NHID / 4);
    dim3 gt(12, 12, 4);
    k_convT<<<gt, 256, 0, stream>>>(Wq, Wk, Wv, Wo, WtQ, WtK, WtV, WtO);
    dim3 gg(6, 32);
    k_gemm_mfma<<<gg, 256, 0, stream>>>(rb, WtQ, bq, qb, nullptr, 0.125f);
    k_gemm_mfma<<<gg, 256, 0, stream>>>(rb, WtK, bk, kb, nullptr, 1.0f);
    k_gemm_mfma<<<gg, 256, 0, stream>>>(xb, WtV, bv, vb, nullptr, 1.0f);
    dim3 ga(NS / 64, NH, NB);
    k_attn<<<ga, 256, 0, stream>>>(qb, kb, vb, am, aob);
    k_gemm_mfma<<<gg, 256, 0, stream>>>(aob, WtO, bo, nullptr, out, 1.0f);
}

// Round 3
// 92.009 us; speedup vs baseline: 5.9323x; 2.2379x over previous
//
#include <hip/hip_runtime.h>
#include <hip/hip_bf16.h>
#include <math.h>

#define NB 2
#define NS 2048
#define NHID 768
#define NH 12
#define NDH 64
#define NWIN 128

typedef __attribute__((ext_vector_type(8))) short bf16x8;
typedef __attribute__((ext_vector_type(4))) float f32x4;

__device__ inline unsigned short f2b(float f) {
    union { float f; unsigned int i; } x; x.f = f;
    unsigned int r = x.i + 0x7FFFu + ((x.i >> 16) & 1u);   // RNE
    return (unsigned short)(r >> 16);
}
__device__ inline void unpack2(unsigned int w, float& lo, float& hi) {
    union { unsigned int i; float f; } a, b;
    a.i = w << 16; b.i = w & 0xFFFF0000u;
    lo = a.f; hi = b.f;
}

// ---------------- RoPE cos/sin table (double precision) ----------------
__global__ void k_rope_table(float* __restrict__ ct, float* __restrict__ st) {
    int idx = blockIdx.x * 256 + threadIdx.x;
    if (idx >= NS * 32) return;
    int s = idx >> 5, f = idx & 31;
    double inv = pow(10000.0, -((double)(2 * f)) / 64.0);
    double ang = (double)s * inv;
    ct[idx] = (float)cos(ang);
    st[idx] = (float)sin(ang);
}

// ---------------- RoPE apply -> bf16 r; also x -> bf16 xb ----------------
__global__ void k_rope(const float* __restrict__ x, const float* __restrict__ ct,
                       const float* __restrict__ st, __hip_bfloat16* __restrict__ r,
                       __hip_bfloat16* __restrict__ xb) {
    int idx = blockIdx.x * 256 + threadIdx.x;  // B*S*H*32 pairs
    if (idx >= NB * NS * NH * 32) return;
    int f = idx & 31;
    int h = (idx >> 5) % NH;
    int bs = idx / (32 * NH);
    int s = bs & (NS - 1);
    int base = bs * NHID + h * NDH;
    float x1 = x[base + f], x2 = x[base + 32 + f];
    float c = ct[(s << 5) + f], sn = st[(s << 5) + f];
    ((unsigned short*)r)[base + f]      = f2b(x1 * c - x2 * sn);
    ((unsigned short*)r)[base + 32 + f] = f2b(x2 * c + x1 * sn);
    ((unsigned short*)xb)[base + f]      = f2b(x1);
    ((unsigned short*)xb)[base + 32 + f] = f2b(x2);
}

// ---------------- weight transpose + convert: Wt[n][k] = bf16(W[k][n]) ----------------
__global__ __launch_bounds__(256) void k_convT(const float* __restrict__ w0, const float* __restrict__ w1,
                                               const float* __restrict__ w2, const float* __restrict__ w3,
                                               __hip_bfloat16* o0, __hip_bfloat16* o1,
                                               __hip_bfloat16* o2, __hip_bfloat16* o3) {
    const float* W; __hip_bfloat16* O;
    switch (blockIdx.z) {
        case 0: W = w0; O = o0; break;
        case 1: W = w1; O = o1; break;
        case 2: W = w2; O = o2; break;
        default: W = w3; O = o3; break;
    }
    __shared__ float tile[64][65];
    int k0 = blockIdx.x * 64, n0 = blockIdx.y * 64;
    int t = threadIdx.x;
    int rr = t >> 4, cc = (t & 15) * 4;
#pragma unroll
    for (int u = 0; u < 4; ++u) {
        int row = rr + u * 16;
        float4 f = *(const float4*)(W + (size_t)(k0 + row) * NHID + n0 + cc);
        tile[row][cc] = f.x; tile[row][cc + 1] = f.y;
        tile[row][cc + 2] = f.z; tile[row][cc + 3] = f.w;
    }
    __syncthreads();
#pragma unroll
    for (int u = 0; u < 4; ++u) {
        int n = rr + u * 16;
        ushort4 s = { f2b(tile[cc + 0][n]), f2b(tile[cc + 1][n]),
                      f2b(tile[cc + 2][n]), f2b(tile[cc + 3][n]) };
        *(ushort4*)((unsigned short*)O + (size_t)(n0 + n) * NHID + k0 + cc) = s;
    }
}

// ---------------- bf16 MFMA GEMM body: C[4096][768] = (A x Wt^T + bias)*scale -------
union Frag { bf16x8 v; unsigned long long q[2]; };

__device__ __forceinline__ void gemm_body(const __hip_bfloat16* __restrict__ A,
                                          const __hip_bfloat16* __restrict__ Wt,
                                          const float* __restrict__ bias,
                                          __hip_bfloat16* __restrict__ Cb,
                                          float* __restrict__ Cf, float scale,
                                          int m0, int n0) {
    __shared__ unsigned short As[128][40];
    __shared__ unsigned short Bs[128][40];
    const int t = threadIdx.x;
    const int wid = t >> 6, lane = t & 63;
    const int wm = (wid >> 1) * 64, wn = (wid & 1) * 64;
    const int g = lane >> 4, r16 = lane & 15;

    f32x4 acc[4][4];
#pragma unroll
    for (int i = 0; i < 4; ++i)
#pragma unroll
        for (int j = 0; j < 4; ++j) acc[i][j] = (f32x4){0.f, 0.f, 0.f, 0.f};

    const int srow = t >> 2, spart = t & 3;
    const __hip_bfloat16* aP = A + (size_t)(m0 + srow) * NHID + spart * 8;
    const __hip_bfloat16* bP = Wt + (size_t)(n0 + srow) * NHID + spart * 8;

    uint4 ra0 = *(const uint4*)(aP);
    uint4 ra1 = *(const uint4*)(aP + 64 * NHID);
    uint4 rb0 = *(const uint4*)(bP);
    uint4 rb1 = *(const uint4*)(bP + 64 * NHID);

    for (int ks = 0; ks < 24; ++ks) {
        __syncthreads();
        *(uint4*)&As[srow][spart * 8]      = ra0;
        *(uint4*)&As[srow + 64][spart * 8] = ra1;
        *(uint4*)&Bs[srow][spart * 8]      = rb0;
        *(uint4*)&Bs[srow + 64][spart * 8] = rb1;
        __syncthreads();
        if (ks < 23) {
            const __hip_bfloat16* a2 = aP + (ks + 1) * 32;
            const __hip_bfloat16* b2 = bP + (ks + 1) * 32;
            ra0 = *(const uint4*)(a2);
            ra1 = *(const uint4*)(a2 + 64 * NHID);
            rb0 = *(const uint4*)(b2);
            rb1 = *(const uint4*)(b2 + 64 * NHID);
        }
        Frag af[4], bf[4];
#pragma unroll
        for (int mi = 0; mi < 4; ++mi) {
            const unsigned short* p = &As[wm + mi * 16 + r16][0];
            af[mi].q[0] = *(const unsigned long long*)(p + 4 * g);
            af[mi].q[1] = *(const unsigned long long*)(p + 16 + 4 * g);
        }
#pragma unroll
        for (int ni = 0; ni < 4; ++ni) {
            const unsigned short* p = &Bs[wn + ni * 16 + r16][0];
            bf[ni].q[0] = *(const unsigned long long*)(p + 4 * g);
            bf[ni].q[1] = *(const unsigned long long*)(p + 16 + 4 * g);
        }
#pragma unroll
        for (int mi = 0; mi < 4; ++mi)
#pragma unroll
            for (int ni = 0; ni < 4; ++ni)
                acc[mi][ni] = __builtin_amdgcn_mfma_f32_16x16x32_bf16(af[mi].v, bf[ni].v, acc[mi][ni], 0, 0, 0);
    }

#pragma unroll
    for (int mi = 0; mi < 4; ++mi)
#pragma unroll
        for (int ni = 0; ni < 4; ++ni)
#pragma unroll
            for (int r = 0; r < 4; ++r) {
                int m = m0 + wm + mi * 16 + 4 * g + r;
                int n = n0 + wn + ni * 16 + r16;
                float v = (acc[mi][ni][r] + bias[n]) * scale;
                if (Cb) ((unsigned short*)Cb)[(size_t)m * NHID + n] = f2b(v);
                else    Cf[(size_t)m * NHID + n] = v;
            }
}

// fused QKV projection: blockIdx.z selects which GEMM
__global__ __launch_bounds__(256) void k_gemm_qkv(const __hip_bfloat16* __restrict__ rb,
                                                  const __hip_bfloat16* __restrict__ xb,
                                                  const __hip_bfloat16* __restrict__ WtQ,
                                                  const __hip_bfloat16* __restrict__ WtK,
                                                  const __hip_bfloat16* __restrict__ WtV,
                                                  const float* __restrict__ bq,
                                                  const float* __restrict__ bk,
                                                  const float* __restrict__ bv,
                                                  __hip_bfloat16* qb, __hip_bfloat16* kb,
                                                  __hip_bfloat16* vb) {
    const __hip_bfloat16 *A, *W; const float* bias; __hip_bfloat16* C; float scale;
    switch (blockIdx.z) {
        case 0:  A = rb; W = WtQ; bias = bq; C = qb; scale = 0.125f; break;
        case 1:  A = rb; W = WtK; bias = bk; C = kb; scale = 1.0f;   break;
        default: A = xb; W = WtV; bias = bv; C = vb; scale = 1.0f;   break;
    }
    gemm_body(A, W, bias, C, nullptr, scale, blockIdx.y * 128, blockIdx.x * 128);
}

__global__ __launch_bounds__(256) void k_gemm_out(const __hip_bfloat16* __restrict__ A,
                                                  const __hip_bfloat16* __restrict__ Wt,
                                                  const float* __restrict__ bias,
                                                  float* __restrict__ Cf) {
    gemm_body(A, Wt, bias, nullptr, Cf, 1.0f, blockIdx.y * 128, blockIdx.x * 128);
}

// ---------------- sliding-window flash attention, MFMA (swapped-QK trick) ------------
// Block = (b, h, 64-query tile), 4 waves x 16 queries. S^T = mfma(K, Q); P^T acc
// feeds PV's B-operand in-lane; O^T = mfma(V^T, P^T). Per-lane online softmax.
__global__ __launch_bounds__(256) void k_attn(const __hip_bfloat16* __restrict__ q,
                                              const __hip_bfloat16* __restrict__ kmat,
                                              const __hip_bfloat16* __restrict__ vmat,
                                              const int* __restrict__ am,
                                              __hip_bfloat16* __restrict__ o) {
    __shared__ unsigned short Ks[64][72];   // [key][d], stride 144B (16B-aligned, b64-floor reads)
    __shared__ unsigned short Vt[64][72];   // [d][key]
    __shared__ float kmask[64];
    const int t = threadIdx.x;
    const int h = blockIdx.y, b = blockIdx.z;
    const int i0 = blockIdx.x * 64;
    const int w = t >> 6, lane = t & 63;
    const int g = lane >> 4, r16 = lane & 15;
    const int qrow = i0 + w * 16 + r16;     // this lane's query row

    Frag qf[2];
    {
        const unsigned short* qp = (const unsigned short*)q + ((size_t)(b * NS) + qrow) * NHID + h * NDH;
        qf[0].q[0] = *(const unsigned long long*)(qp + 4 * g);
        qf[0].q[1] = *(const unsigned long long*)(qp + 16 + 4 * g);
        qf[1].q[0] = *(const unsigned long long*)(qp + 32 + 4 * g);
        qf[1].q[1] = *(const unsigned long long*)(qp + 48 + 4 * g);
    }
    float m_run = -1e30f, l_run = 0.f;
    f32x4 oacc[4];
#pragma unroll
    for (int i = 0; i < 4; ++i) oacc[i] = (f32x4){0.f, 0.f, 0.f, 0.f};

    for (int kt = 0; kt < 5; ++kt) {
        const int j0 = i0 - 128 + kt * 64;
        if (j0 < 0 || j0 >= NS) continue;   // tiles are always fully in/out of range
        {   // stage K [key][d]
            int key = t >> 2, p = t & 3;
            const unsigned short* kp = (const unsigned short*)kmat +
                ((size_t)(b * NS) + j0 + key) * NHID + h * NDH + p * 16;
            uint4 u0 = *(const uint4*)kp;
            uint4 u1 = *(const uint4*)(kp + 8);
            *(uint4*)&Ks[key][p * 16]     = u0;
            *(uint4*)&Ks[key][p * 16 + 8] = u1;
        }
        {   // stage V transposed: pair two keys per b32 write (conflict-free)
            int kp2 = t & 31, c = t >> 5;   // 32 key-pairs, 8 d-chunks
            const unsigned short* vp = (const unsigned short*)vmat +
                ((size_t)(b * NS) + j0 + 2 * kp2) * NHID + h * NDH + c * 8;
            uint4 v0 = *(const uint4*)vp;
            uint4 v1 = *(const uint4*)(vp + NHID);
            union { uint4 u; unsigned short s[8]; } a0, a1;
            a0.u = v0; a1.u = v1;
#pragma unroll
            for (int e = 0; e < 8; ++e) {
                unsigned int pk = (unsigned int)a0.s[e] | ((unsigned int)a1.s[e] << 16);
                *(unsigned int*)&Vt[c * 8 + e][2 * kp2] = pk;
            }
        }
        if (t < 64) kmask[t] = (am[b * NS + j0 + t] != 0) ? 0.f : -1e30f;
        __syncthreads();

        // S^T = K . Q^T  (m=key, n=q, contract d)
        f32x4 sacc[4];
#pragma unroll
        for (int i = 0; i < 4; ++i) sacc[i] = (f32x4){0.f, 0.f, 0.f, 0.f};
#pragma unroll
        for (int mi = 0; mi < 4; ++mi) {
            Frag kf0, kf1;
            const unsigned short* pk = &Ks[mi * 16 + r16][0];
            kf0.q[0] = *(const unsigned long long*)(pk + 4 * g);
            kf0.q[1] = *(const unsigned long long*)(pk + 16 + 4 * g);
            kf1.q[0] = *(const unsigned long long*)(pk + 32 + 4 * g);
            kf1.q[1] = *(const unsigned long long*)(pk + 48 + 4 * g);
            sacc[mi] = __builtin_amdgcn_mfma_f32_16x16x32_bf16(kf0.v, qf[0].v, sacc[mi], 0, 0, 0);
            sacc[mi] = __builtin_amdgcn_mfma_f32_16x16x32_bf16(kf1.v, qf[1].v, sacc[mi], 0, 0, 0);
        }

        // mask + per-lane online softmax (lane owns q=qrow; 16 key-values here)
        float p[4][4];
        float tmax = -1e30f;
#pragma unroll
        for (int mi = 0; mi < 4; ++mi)
#pragma unroll
            for (int r = 0; r < 4; ++r) {
                int key = j0 + mi * 16 + 4 * g + r;
                float s = sacc[mi][r] + kmask[mi * 16 + 4 * g + r];
                int d = qrow - key; d = d < 0 ? -d : d;
                if (d >= NWIN) s = -1e30f;
                p[mi][r] = s;
                tmax = fmaxf(tmax, s);
            }
        tmax = fmaxf(tmax, __shfl_xor(tmax, 16));
        tmax = fmaxf(tmax, __shfl_xor(tmax, 32));
        float mnew = fmaxf(m_run, tmax);
        float psum = 0.f;
#pragma unroll
        for (int mi = 0; mi < 4; ++mi)
#pragma unroll
            for (int r = 0; r < 4; ++r) {
                float pv = __expf(p[mi][r] - mnew);
                p[mi][r] = pv;
                psum += pv;
            }
        psum += __shfl_xor(psum, 16);
        psum += __shfl_xor(psum, 32);
        float alpha = __expf(m_run - mnew);
        m_run = mnew;
        l_run = l_run * alpha + psum;
#pragma unroll
        for (int mi = 0; mi < 4; ++mi)
#pragma unroll
            for (int r = 0; r < 4; ++r) oacc[mi][r] *= alpha;

        // pack P^T fragments (in-lane: acc layout == B-operand layout)
        Frag pf[2];
#pragma unroll
        for (int ks2 = 0; ks2 < 2; ++ks2) {
            union { bf16x8 v; unsigned short s[8]; } pp;
#pragma unroll
            for (int r = 0; r < 4; ++r) {
                pp.s[r]     = f2b(p[2 * ks2][r]);
                pp.s[r + 4] = f2b(p[2 * ks2 + 1][r]);
            }
            pf[ks2].v = pp.v;
        }

        // O^T += V^T . P^T  (m=d, n=q, contract key)
#pragma unroll
        for (int mi = 0; mi < 4; ++mi) {
            Frag vf0, vf1;
            const unsigned short* pv = &Vt[mi * 16 + r16][0];
            vf0.q[0] = *(const unsigned long long*)(pv + 4 * g);
            vf0.q[1] = *(const unsigned long long*)(pv + 16 + 4 * g);
            vf1.q[0] = *(const unsigned long long*)(pv + 32 + 4 * g);
            vf1.q[1] = *(const unsigned long long*)(pv + 48 + 4 * g);
            oacc[mi] = __builtin_amdgcn_mfma_f32_16x16x32_bf16(vf0.v, pf[0].v, oacc[mi], 0, 0, 0);
            oacc[mi] = __builtin_amdgcn_mfma_f32_16x16x32_bf16(vf1.v, pf[1].v, oacc[mi], 0, 0, 0);
        }
        __syncthreads();
    }

    float inv_l = 1.0f / l_run;
    unsigned short* op = (unsigned short*)o + ((size_t)(b * NS) + qrow) * NHID + h * NDH;
#pragma unroll
    for (int mi = 0; mi < 4; ++mi) {
        ushort4 s = { f2b(oacc[mi][0] * inv_l), f2b(oacc[mi][1] * inv_l),
                      f2b(oacc[mi][2] * inv_l), f2b(oacc[mi][3] * inv_l) };
        *(ushort4*)(op + mi * 16 + 4 * g) = s;
    }
}

extern "C" void kernel_launch(void* const* d_in, const int* in_sizes, int n_in,
                              void* d_out, int out_size, void* d_ws, size_t ws_size,
                              hipStream_t stream) {
    (void)in_sizes; (void)n_in; (void)out_size; (void)ws_size;
    const float* x  = (const float*)d_in[0];
    const int*   am = (const int*)d_in[1];
    const float* Wq = (const float*)d_in[2];
    const float* bq = (const float*)d_in[3];
    const float* Wk = (const float*)d_in[4];
    const float* bk = (const float*)d_in[5];
    const float* Wv = (const float*)d_in[6];
    const float* bv = (const float*)d_in[7];
    const float* Wo = (const float*)d_in[8];
    const float* bo = (const float*)d_in[9];
    float* out = (float*)d_out;
    float* ws  = (float*)d_ws;

    float* ct = ws;                                          // 65536
    float* st = ws + 65536;                                  // 65536
    __hip_bfloat16* rb  = (__hip_bfloat16*)(ws + 131072);    // 4096x768 bf16
    __hip_bfloat16* xb  = (__hip_bfloat16*)(ws + 1703936);
    __hip_bfloat16* WtQ = (__hip_bfloat16*)(ws + 3276800);   // 768x768 bf16 each
    __hip_bfloat16* WtK = (__hip_bfloat16*)(ws + 3571712);
    __hip_bfloat16* WtV = (__hip_bfloat16*)(ws + 3866624);
    __hip_bfloat16* WtO = (__hip_bfloat16*)(ws + 4161536);
    __hip_bfloat16* qb  = (__hip_bfloat16*)(ws + 4456448);   // 4096x768 bf16
    __hip_bfloat16* kb  = (__hip_bfloat16*)(ws + 6029312);
    __hip_bfloat16* vb  = (__hip_bfloat16*)(ws + 7602176);
    __hip_bfloat16* aob = (__hip_bfloat16*)(ws + 9175040);

    k_rope_table<<<256, 256, 0, stream>>>(ct, st);
    k_rope<<<(NB * NS * NH * 32 + 255) / 256, 256, 0, stream>>>(x, ct, st, rb, xb);
    dim3 gt(12, 12, 4);
    k_convT<<<gt, 256, 0, stream>>>(Wq, Wk, Wv, Wo, WtQ, WtK, WtV, WtO);
    dim3 gq(6, 32, 3);
    k_gemm_qkv<<<gq, 256, 0, stream>>>(rb, xb, WtQ, WtK, WtV, bq, bk, bv, qb, kb, vb);
    dim3 ga(NS / 64, NH, NB);
    k_attn<<<ga, 256, 0, stream>>>(qb, kb, vb, am, aob);
    dim3 gg(6, 32);
    k_gemm_out<<<gg, 256, 0, stream>>>(aob, WtO, bo, out);
}